// Round 11
// baseline (1183.355 us; speedup 1.0000x reference)
//
#include <hip/hip_runtime.h>
#include <cstdint>
#include <cstddef>

// ---------------------------------------------------------------------------
// ShuffleWindowAttention, MI355X (gfx950)
// B=4, N=50176, C=512, WS=49, w=1024 windows/batch, NH=8, hd=64
// Pipeline (window-major intermediates):
//   prep_weights ; prep_x (fp32->bf16, token->window-major gather)
//   -> QKV GEMM (256^2, R9 counted-vmcnt schedule)
//   -> FUSED attention+proj (O kept in LDS, proj weights from L2,
//      permuted fp32 store to token-major out).
// Window-major row: m = b*50176 + wi*49 + s <-> token t = b*50176 + s*1024 + wi.
// ---------------------------------------------------------------------------

typedef __bf16 bf16x8 __attribute__((ext_vector_type(8)));
typedef __bf16 bf16x4 __attribute__((ext_vector_type(4)));
typedef float  f32x4  __attribute__((ext_vector_type(4)));

#define MFMA_BF16(a, b, c) __builtin_amdgcn_mfma_f32_16x16x32_bf16((a), (b), (c), 0, 0, 0)

static __device__ __forceinline__ int swzi(int row, int col) {
  return col ^ ((row & 7) << 3);   // attn swizzle (128B rows)
}

typedef __attribute__((address_space(1))) const void gconst_t;
typedef __attribute__((address_space(3))) void lds_t;
static __device__ __forceinline__ void gload16(const void* g, void* l) {
  __builtin_amdgcn_global_load_lds((gconst_t*)g, (lds_t*)l, 16, 0, 0);
}

#define WAITV2()   asm volatile("s_waitcnt vmcnt(2)" ::: "memory")
#define WAITV0()   asm volatile("s_waitcnt vmcnt(0)" ::: "memory")

// window-major row -> token row
static __device__ __forceinline__ int wm2tok(int m) {
  const int b   = m / 50176;
  const int rem = m - b * 50176;
  const int wi  = rem / 49;
  const int s   = rem - wi * 49;
  return b * 50176 + s * 1024 + wi;
}

// ---------------------------------------------------------------------------
__global__ void prep_weights(const float* __restrict__ wqkv,
                             const float* __restrict__ bqkv,
                             const float* __restrict__ wproj,
                             __bf16* __restrict__ wqkv_bf,
                             __bf16* __restrict__ wproj_bf,
                             float* __restrict__ bq_s) {
  const int stride = gridDim.x * blockDim.x;
  const int t0 = blockIdx.x * blockDim.x + threadIdx.x;
  for (int i = t0; i < 1536 * 512; i += stride) {
    float v = wqkv[i];
    if (i < 512 * 512) v *= 0.125f;
    wqkv_bf[i] = (__bf16)v;
  }
  for (int i = t0; i < 512 * 512; i += stride) wproj_bf[i] = (__bf16)wproj[i];
  for (int i = t0; i < 1536; i += stride)      bq_s[i] = (i < 512 ? 0.125f : 1.0f) * bqkv[i];
}

// x: fp32 token-major [200704][512] -> bf16 WINDOW-MAJOR [200704][512]
__global__ void prep_x(const float* __restrict__ x, __bf16* __restrict__ xb) {
  const size_t total  = (size_t)200704 * 64;   // 8-elem groups
  const size_t stride = (size_t)gridDim.x * blockDim.x;
  for (size_t i = (size_t)blockIdx.x * blockDim.x + threadIdx.x; i < total; i += stride) {
    const int m  = (int)(i >> 6);              // window-major out row
    const int c8 = ((int)i & 63) * 8;
    const size_t t = (size_t)wm2tok(m);        // token-major src row
    const float4 a = *(const float4*)(x + t * 512 + c8);
    const float4 b = *(const float4*)(x + t * 512 + c8 + 4);
    bf16x8 v;
    v[0] = (__bf16)a.x; v[1] = (__bf16)a.y; v[2] = (__bf16)a.z; v[3] = (__bf16)a.w;
    v[4] = (__bf16)b.x; v[5] = (__bf16)b.y; v[6] = (__bf16)b.z; v[7] = (__bf16)b.w;
    *(bf16x8*)(xb + i * 8) = v;
  }
}

// ---------------------------------------------------------------------------
// 256x256-tile GEMM (R9 schedule, verbatim): counted WAITV(2) tile gate,
// staggered half-tile staging through drift phases, end-of-tile barrier.
// ---------------------------------------------------------------------------
template<bool OUT_F32, bool PERM_OUT>
__launch_bounds__(512, 2)
__global__ void gemm256(const __bf16* __restrict__ Ab,   // [M][512]
                        const __bf16* __restrict__ Bw,   // [N][512]
                        const float* __restrict__ bias,  // [N]
                        void* __restrict__ Cv,
                        int Mtiles, int Ntiles) {
  __shared__ __align__(16) __bf16 sA[2][256 * 64];
  __shared__ __align__(16) __bf16 sB[2][256 * 64];

  const int tid  = threadIdx.x;
  const int lane = tid & 63;
  const int l15  = lane & 15;
  const int kgc  = (lane >> 4) & 3;     // k-chunk within 32-k slice
  const int r4   = kgc * 4;             // C/D row group
  const int wv   = tid >> 6;            // 0..7
  const int wm   = wv >> 2, wn = wv & 3;

  const int nwg = Mtiles * Ntiles;
  const int cpx = nwg >> 3;                       // nwg % 8 == 0
  const int wg  = (blockIdx.x & 7) * cpx + (blockIdx.x >> 3);
  const int mt  = wg / Ntiles;                    // M-outer: A-tile L2 reuse
  const int nt  = wg % Ntiles;
  const size_t m0 = (size_t)mt * 256;
  const int    n0 = nt * 256;

  const int srow   = tid >> 3;                    // 0..63
  const int schunk = (tid & 7) ^ (srow & 7);

  f32x4 acc[8][4];
  const f32x4 zf = {0.f, 0.f, 0.f, 0.f};
#pragma unroll
  for (int i = 0; i < 8; ++i)
#pragma unroll
    for (int j = 0; j < 4; ++j) acc[i][j] = zf;

  auto STAGE_HALF = [&](int bufi, int kt, int mat, int h) {
    const size_t kof = (size_t)kt * 64 + schunk * 8;
    const __bf16* src = mat ? Bw : Ab;
    const size_t base0 = mat ? (size_t)n0 : m0;
    __bf16* dst = (mat ? &sB[bufi][0] : &sA[bufi][0]) + h * 8192 + tid * 8;
#pragma unroll
    for (int j = 0; j < 2; ++j)
      gload16(src + (base0 + (size_t)(h * 128 + j * 64 + srow)) * 512 + kof,
              dst + j * 4096);
  };

  auto LDB = [&](int bufi, int ks, bf16x8* bfrag) {
#pragma unroll
    for (int n = 0; n < 4; ++n) {
      const int r = wn * 64 + n * 16 + l15;
      bfrag[n] = *(const bf16x8*)&sB[bufi][r * 64 + (((ks * 4 + kgc) ^ (r & 7)) * 8)];
    }
  };
  auto LDA = [&](int bufi, int mh, int ks, bf16x8* afrag) {
#pragma unroll
    for (int m2 = 0; m2 < 4; ++m2) {
      const int r = wm * 128 + mh * 64 + m2 * 16 + l15;
      afrag[m2] = *(const bf16x8*)&sA[bufi][r * 64 + (((ks * 4 + kgc) ^ (r & 7)) * 8)];
    }
  };
  auto MM = [&](int mh, const bf16x8* afrag, const bf16x8* bfrag) {
    __builtin_amdgcn_s_setprio(1);
#pragma unroll
    for (int m2 = 0; m2 < 4; ++m2)
#pragma unroll
      for (int n = 0; n < 4; ++n)
        acc[mh * 4 + m2][n] = MFMA_BF16(afrag[m2], bfrag[n], acc[mh * 4 + m2][n]);
    __builtin_amdgcn_s_setprio(0);
  };

  // prologue: all 4 half-tiles of K-tile 0 -> buf 0 (8 loads in flight)
  STAGE_HALF(0, 0, 0, 0); STAGE_HALF(0, 0, 0, 1);
  STAGE_HALF(0, 0, 1, 0); STAGE_HALF(0, 0, 1, 1);

  int buf = 0;
  for (int t = 0; t < 8; ++t) {
    const int nxt = buf ^ 1;
    if (t < 7) { STAGE_HALF(nxt, t + 1, 0, 0); WAITV2(); }
    else       { WAITV0(); }
    __builtin_amdgcn_s_barrier();
    __builtin_amdgcn_sched_barrier(0);

    bf16x8 b0[4], b1[4], a[4];
    // phase 0: (ks0, mh0)
    LDB(buf, 0, b0);
    LDA(buf, 0, 0, a);
    MM(0, a, b0);
    // phase 1: (ks0, mh1)   + stage Ah1(t+1)
    if (t < 7) STAGE_HALF(nxt, t + 1, 0, 1);
    LDA(buf, 1, 0, a);
    MM(1, a, b0);
    // phase 2: (ks1, mh0)   + stage Bh0(t+1)
    if (t < 7) STAGE_HALF(nxt, t + 1, 1, 0);
    LDB(buf, 1, b1);
    LDA(buf, 0, 1, a);
    MM(0, a, b1);
    // phase 3: (ks1, mh1)   + stage Bh1(t+1)
    if (t < 7) STAGE_HALF(nxt, t + 1, 1, 1);
    LDA(buf, 1, 1, a);
    MM(1, a, b1);

    // end-of-tile barrier: all waves done reading buf
    __builtin_amdgcn_sched_barrier(0);
    __builtin_amdgcn_s_barrier();
    buf = nxt;
  }

  // ---- epilogue ----
  const int Nld = Ntiles * 256;
#pragma unroll
  for (int m = 0; m < 8; ++m) {
#pragma unroll
    for (int r = 0; r < 4; ++r) {
      const int row = (int)m0 + wm * 128 + m * 16 + r4 + r;   // window-major
      const size_t orow = PERM_OUT ? (size_t)wm2tok(row) : (size_t)row;
#pragma unroll
      for (int n = 0; n < 4; ++n) {
        const int col = n0 + wn * 64 + n * 16 + l15;
        const float v = acc[m][n][r] + bias[col];
        if (OUT_F32) ((float*)Cv)[orow * (size_t)Nld + col] = v;
        else         ((__bf16*)Cv)[orow * (size_t)Nld + col] = (__bf16)v;
      }
    }
  }
}

// ---------------------------------------------------------------------------
// FUSED windowed attention + proj: one block (8 waves) per window, wave=head.
// qkv WINDOW-MAJOR [blk*49+s][1536] bf16 in; out token-major fp32.
// After PV, wave h writes its O block (49x64) into the dead vT[h] LDS region
// (bv fragments already in registers). Barrier, then all 8 waves compute
// out = O @ Wproj^T + bproj, streaming Wproj (512 KB, L2-resident) and
// storing to the R1-proven scattered token-major layout.
// ---------------------------------------------------------------------------
__launch_bounds__(512)
__global__ void attn_proj(const __bf16* __restrict__ qkv,
                          const __bf16* __restrict__ wproj_bf,
                          const float* __restrict__ bproj,
                          float* __restrict__ out) {
  __shared__ __align__(16) __bf16 vT[8 * 64 * 64];   // V^T, then O blocks
  __shared__ __align__(16) __bf16 sP[8][16 * 64];    // per-wave P tile

  const int tid  = threadIdx.x;
  const int lane = tid & 63;
  const int h    = tid >> 6;                 // wave = head
  const int l15  = lane & 15;
  const int kg   = ((lane >> 4) & 3) * 8;
  const int r4   = ((lane >> 4) & 3) * 4;

  const int blk = blockIdx.x;
  const size_t wbase   = (size_t)blk * 49;            // window-major row base
  const size_t tokbase = (size_t)(blk >> 10) * 50176 + (blk & 1023);

  const int MOFF[4] = {0, 16, 32, 33};
  const float NEG_INF = -__builtin_inff();

  // ---- issue q,k fragment loads early (overlap with V staging) ----
  bf16x8 aq[4][2], bk[4][2];
#pragma unroll
  for (int mt = 0; mt < 4; ++mt) {
    const size_t tok = wbase + (size_t)(MOFF[mt] + l15);
#pragma unroll
    for (int ks = 0; ks < 2; ++ks) {
      aq[mt][ks] = *(const bf16x8*)(qkv + tok * 1536 +       h * 64 + ks * 32 + kg);
      bk[mt][ks] = *(const bf16x8*)(qkv + tok * 1536 + 512 + h * 64 + ks * 32 + kg);
    }
  }

  // ---- zero vT pad rows k = 49..63 ----
  for (int i = tid; i < 8 * 64 * 16; i += 512) {
    const int k = 48 + (i & 15);
    if (k != 48) {
      const int n  = (i >> 4) & 63;
      const int hh = i >> 10;
      vT[hh * 4096 + n * 64 + (k ^ ((n & 7) << 3))] = (__bf16)0.0f;
    }
  }
  // ---- stage V transposed (+swizzled); reads fully contiguous ----
  for (int i = tid; i < 49 * 64; i += 512) {
    const int s  = i >> 6;
    const int c8 = (i & 63) * 8;
    bf16x8 v8 = *(const bf16x8*)(qkv + (wbase + s) * 1536 + 1024 + c8);
    const int hh = c8 >> 6;
#pragma unroll
    for (int j = 0; j < 8; ++j) {
      const int n = (c8 & 63) + j;
      vT[hh * 4096 + n * 64 + (s ^ ((n & 7) << 3))] = v8[j];
    }
  }
  __syncthreads();

  // ---- V fragments (into registers; vT[h] becomes dead after this) ----
  bf16x8 bv[4][2];
#pragma unroll
  for (int ntv = 0; ntv < 4; ++ntv) {
    const int n = ntv * 16 + l15;
#pragma unroll
    for (int ks = 0; ks < 2; ++ks)
      bv[ntv][ks] = *(const bf16x8*)&vT[h * 4096 + n * 64 + ((ks * 32 + kg) ^ ((n & 7) << 3))];
  }

  // ---- S = q k^T ----
  f32x4 accS[4][4];
  const f32x4 zf = {0.f, 0.f, 0.f, 0.f};
#pragma unroll
  for (int m = 0; m < 4; ++m)
#pragma unroll
    for (int n = 0; n < 4; ++n) accS[m][n] = zf;
#pragma unroll
  for (int ks = 0; ks < 2; ++ks)
#pragma unroll
    for (int m = 0; m < 4; ++m)
#pragma unroll
      for (int n = 0; n < 4; ++n)
        accS[m][n] = MFMA_BF16(aq[m][ks], bk[n][ks], accS[m][n]);

  // ---- per row-tile: softmax -> P (LDS) -> PV -> O into vT[h] ----
#pragma unroll
  for (int mt = 0; mt < 4; ++mt) {
#pragma unroll
    for (int r = 0; r < 4; ++r) {
      const int prow = r4 + r;
      const float sv0 = accS[mt][0][r];
      const float sv1 = accS[mt][1][r];
      const float sv2 = accS[mt][2][r];
      const float sv3 = (l15 == 15) ? accS[mt][3][r] : NEG_INF;
      float mx = fmaxf(fmaxf(sv0, sv1), fmaxf(sv2, sv3));
      mx = fmaxf(mx, __shfl_xor(mx, 1));
      mx = fmaxf(mx, __shfl_xor(mx, 2));
      mx = fmaxf(mx, __shfl_xor(mx, 4));
      mx = fmaxf(mx, __shfl_xor(mx, 8));
      const float e0 = __expf(sv0 - mx);
      const float e1 = __expf(sv1 - mx);
      const float e2 = __expf(sv2 - mx);
      const float e3 = __expf(sv3 - mx);      // 0 for masked lanes
      float sum = e0 + e1 + e2 + e3;
      sum += __shfl_xor(sum, 1);
      sum += __shfl_xor(sum, 2);
      sum += __shfl_xor(sum, 4);
      sum += __shfl_xor(sum, 8);
      const float inv = 1.0f / sum;
      sP[h][prow * 64 + swzi(prow, 0  + l15)] = (__bf16)(e0 * inv);
      sP[h][prow * 64 + swzi(prow, 16 + l15)] = (__bf16)(e1 * inv);
      sP[h][prow * 64 + swzi(prow, 32 + l15)] = (__bf16)(e2 * inv);
      if (l15 == 15) sP[h][prow * 64 + swzi(prow, 48)] = (__bf16)(e3 * inv);
      if (l15 < 15)  sP[h][prow * 64 + swzi(prow, 49 + l15)] = (__bf16)0.0f;
    }
    bf16x8 ap[2];
#pragma unroll
    for (int ks = 0; ks < 2; ++ks)
      ap[ks] = *(const bf16x8*)&sP[h][l15 * 64 + swzi(l15, ks * 32 + kg)];
    f32x4 accO[4];
#pragma unroll
    for (int n = 0; n < 4; ++n) accO[n] = zf;
#pragma unroll
    for (int ks = 0; ks < 2; ++ks)
#pragma unroll
      for (int n = 0; n < 4; ++n)
        accO[n] = MFMA_BF16(ap[ks], bv[n][ks], accO[n]);
    // O block for this head -> vT[h] region (overlap rows duplicate-benign)
#pragma unroll
    for (int n = 0; n < 4; ++n) {
#pragma unroll
      for (int r = 0; r < 4; ++r) {
        const int row = MOFF[mt] + r4 + r;
        vT[h * 4096 + row * 64 + swzi(row, n * 16 + l15)] = (__bf16)accO[n][r];
      }
    }
  }
  __syncthreads();   // all heads' O blocks complete in LDS

  // ---- proj: out = O @ Wproj^T + bproj ; wave h covers cols h*64..+63 ----
  f32x4 accF[4][4];
#pragma unroll
  for (int m = 0; m < 4; ++m)
#pragma unroll
    for (int n = 0; n < 4; ++n) accF[m][n] = zf;

  for (int hh = 0; hh < 8; ++hh) {
#pragma unroll
    for (int ks2 = 0; ks2 < 2; ++ks2) {
      bf16x8 ao[4], bw[4];
#pragma unroll
      for (int mt = 0; mt < 4; ++mt) {
        const int row = MOFF[mt] + l15;
        ao[mt] = *(const bf16x8*)&vT[hh * 4096 + row * 64 + swzi(row, ks2 * 32 + kg)];
      }
#pragma unroll
      for (int n = 0; n < 4; ++n) {
        const int cc = h * 64 + n * 16 + l15;
        bw[n] = *(const bf16x8*)(wproj_bf + (size_t)cc * 512 + hh * 64 + ks2 * 32 + kg);
      }
#pragma unroll
      for (int mt = 0; mt < 4; ++mt)
#pragma unroll
        for (int n = 0; n < 4; ++n)
          accF[mt][n] = MFMA_BF16(ao[mt], bw[n], accF[mt][n]);
    }
  }

  // ---- store token-major fp32 (dedup overlapped rows) ----
#pragma unroll
  for (int n = 0; n < 4; ++n) {
    const int cc = h * 64 + n * 16 + l15;
    const float bp = bproj[cc];
#pragma unroll
    for (int mt = 0; mt < 4; ++mt) {
#pragma unroll
      for (int r = 0; r < 4; ++r) {
        const int row = MOFF[mt] + r4 + r;
        if (mt < 3 || (r4 + r) == 15) {
          out[(tokbase + (size_t)row * 1024) * 512 + cc] = accF[mt][n][r] + bp;
        }
      }
    }
  }
}

// ===========================================================================
// Fallback: round-1 fused kernel (used only if ws_size is too small).
// ===========================================================================
__launch_bounds__(256, 2)
__global__ void swin_attn_fused(const float* __restrict__ x,
                                const __bf16* __restrict__ wqkv_bf,
                                const float* __restrict__ bq_s,
                                const __bf16* __restrict__ wproj_bf,
                                const float* __restrict__ bproj,
                                float* __restrict__ out) {
  __shared__ __align__(16) __bf16 s_xw[49 * 512];
  __shared__ __align__(16) __bf16 s_q [49 * 64];
  __shared__ __align__(16) __bf16 s_k [49 * 64];
  __shared__ __align__(16) __bf16 s_vT[64 * 64];
  __shared__ __align__(16) __bf16 s_p [49 * 64];

  const int tid  = threadIdx.x;
  const int lane = tid & 63;
  const int wv   = tid >> 6;
  const int l15  = lane & 15;
  const int kg   = (lane >> 4) * 8;
  const int r4   = (lane >> 4) * 4;
  const int blk = blockIdx.x;
  const int b   = blk >> 10;
  const int wi  = blk & 1023;
  const int MOFF[4] = {0, 16, 32, 33};
  const float NEG_INF = -__builtin_inff();

  for (int i = tid; i < 64 * 64; i += 256) s_vT[i] = (__bf16)0.0f;
  const float* xwin = x + ((size_t)b * 50176 + (size_t)wi) * 512;
  for (int idx = tid; idx < 49 * 128; idx += 256) {
    const int row = idx >> 7;
    const int c4  = (idx & 127) * 4;
    const float4 v = *(const float4*)(xwin + (size_t)row * (1024 * 512) + c4);
    bf16x4 t;
    t.x = (__bf16)v.x; t.y = (__bf16)v.y; t.z = (__bf16)v.z; t.w = (__bf16)v.w;
    *(bf16x4*)&s_xw[row * 512 + swzi(row, c4)] = t;
  }
  f32x4 accF[4][8];
  const f32x4 zf = {0.f, 0.f, 0.f, 0.f};
#pragma unroll
  for (int m = 0; m < 4; ++m)
#pragma unroll
    for (int n = 0; n < 8; ++n) accF[m][n] = zf;
  __syncthreads();

  for (int h = 0; h < 8; ++h) {
    f32x4 accA[4][3];
#pragma unroll
    for (int m = 0; m < 4; ++m)
#pragma unroll
      for (int n = 0; n < 3; ++n) accA[m][n] = zf;
    const __bf16* pB[3];
    float biasv[3];
#pragma unroll
    for (int nt = 0; nt < 3; ++nt) {
      const int c  = wv * 48 + nt * 16 + l15;
      const int wr = (c < 64) ? (h * 64 + c)
                   : (c < 128) ? (512 + h * 64 + (c - 64))
                               : (1024 + h * 64 + (c - 128));
      pB[nt]    = wqkv_bf + (size_t)wr * 512 + kg;
      biasv[nt] = bq_s[wr];
    }
#pragma unroll
    for (int ks = 0; ks < 16; ++ks) {
      bf16x8 a[4], bb[3];
#pragma unroll
      for (int mt = 0; mt < 4; ++mt) {
        const int row = MOFF[mt] + l15;
        a[mt] = *(const bf16x8*)&s_xw[row * 512 + swzi(row, ks * 32 + kg)];
      }
#pragma unroll
      for (int nt = 0; nt < 3; ++nt) bb[nt] = *(const bf16x8*)(pB[nt] + ks * 32);
#pragma unroll
      for (int mt = 0; mt < 4; ++mt)
#pragma unroll
        for (int nt = 0; nt < 3; ++nt)
          accA[mt][nt] = MFMA_BF16(a[mt], bb[nt], accA[mt][nt]);
    }
#pragma unroll
    for (int nt = 0; nt < 3; ++nt) {
      const int c = wv * 48 + nt * 16 + l15;
#pragma unroll
      for (int mt = 0; mt < 4; ++mt) {
#pragma unroll
        for (int r = 0; r < 4; ++r) {
          const int row = MOFF[mt] + r4 + r;
          const __bf16 bvv = (__bf16)(accA[mt][nt][r] + biasv[nt]);
          if (c < 64)       s_q[row * 64 + swzi(row, c)] = bvv;
          else if (c < 128) s_k[row * 64 + swzi(row, c - 64)] = bvv;
          else {
            const int vr = c - 128;
            s_vT[vr * 64 + swzi(vr, row)] = bvv;
          }
        }
      }
    }
    __syncthreads();

    const int R = MOFF[wv];
    bf16x8 aq[2], bkf[4][2];
#pragma unroll
    for (int ks2 = 0; ks2 < 2; ++ks2) {
      const int row = R + l15;
      aq[ks2] = *(const bf16x8*)&s_q[row * 64 + swzi(row, ks2 * 32 + kg)];
    }
#pragma unroll
    for (int nt = 0; nt < 4; ++nt) {
      const int row = MOFF[nt] + l15;
#pragma unroll
      for (int ks2 = 0; ks2 < 2; ++ks2)
        bkf[nt][ks2] = *(const bf16x8*)&s_k[row * 64 + swzi(row, ks2 * 32 + kg)];
    }
    f32x4 accS[4];
#pragma unroll
    for (int n = 0; n < 4; ++n) accS[n] = zf;
#pragma unroll
    for (int ks2 = 0; ks2 < 2; ++ks2)
#pragma unroll
      for (int nt = 0; nt < 4; ++nt)
        accS[nt] = MFMA_BF16(aq[ks2], bkf[nt][ks2], accS[nt]);
#pragma unroll
    for (int r = 0; r < 4; ++r) {
      const int row = R + r4 + r;
      const float sv0 = accS[0][r];
      const float sv1 = accS[1][r];
      const float sv2 = accS[2][r];
      const float sv3 = (l15 == 15) ? accS[3][r] : NEG_INF;
      float m = fmaxf(fmaxf(sv0, sv1), fmaxf(sv2, sv3));
      m = fmaxf(m, __shfl_xor(m, 1));
      m = fmaxf(m, __shfl_xor(m, 2));
      m = fmaxf(m, __shfl_xor(m, 4));
      m = fmaxf(m, __shfl_xor(m, 8));
      const float e0 = __expf(sv0 - m);
      const float e1 = __expf(sv1 - m);
      const float e2 = __expf(sv2 - m);
      const float e3 = __expf(sv3 - m);
      float s = e0 + e1 + e2 + e3;
      s += __shfl_xor(s, 1);
      s += __shfl_xor(s, 2);
      s += __shfl_xor(s, 4);
      s += __shfl_xor(s, 8);
      const float inv = 1.0f / s;
      s_p[row * 64 + swzi(row, 0  + l15)] = (__bf16)(e0 * inv);
      s_p[row * 64 + swzi(row, 16 + l15)] = (__bf16)(e1 * inv);
      s_p[row * 64 + swzi(row, 32 + l15)] = (__bf16)(e2 * inv);
      if (l15 == 15) s_p[row * 64 + swzi(row, 48)] = (__bf16)(e3 * inv);
      if (l15 < 15)  s_p[row * 64 + swzi(row, 49 + l15)] = (__bf16)0.0f;
    }
    bf16x8 ap[2], bv2[4][2];
#pragma unroll
    for (int ks2 = 0; ks2 < 2; ++ks2) {
      const int row = R + l15;
      ap[ks2] = *(const bf16x8*)&s_p[row * 64 + swzi(row, ks2 * 32 + kg)];
    }
#pragma unroll
    for (int nt = 0; nt < 4; ++nt) {
      const int row = nt * 16 + l15;
#pragma unroll
      for (int ks2 = 0; ks2 < 2; ++ks2)
        bv2[nt][ks2] = *(const bf16x8*)&s_vT[row * 64 + swzi(row, ks2 * 32 + kg)];
    }
    __syncthreads();
    f32x4 accO[4];
#pragma unroll
    for (int n = 0; n < 4; ++n) accO[n] = zf;
#pragma unroll
    for (int ks2 = 0; ks2 < 2; ++ks2)
#pragma unroll
      for (int nt = 0; nt < 4; ++nt)
        accO[nt] = MFMA_BF16(ap[ks2], bv2[nt][ks2], accO[nt]);
#pragma unroll
    for (int nt = 0; nt < 4; ++nt) {
#pragma unroll
      for (int r = 0; r < 4; ++r) {
        const int row = R + r4 + r;
        s_p[row * 64 + swzi(row, nt * 16 + l15)] = (__bf16)accO[nt][r];
      }
    }
    __syncthreads();
#pragma unroll
    for (int ks2 = 0; ks2 < 2; ++ks2) {
      bf16x8 ao[4], bw[8];
#pragma unroll
      for (int mt = 0; mt < 4; ++mt) {
        const int row = MOFF[mt] + l15;
        ao[mt] = *(const bf16x8*)&s_p[row * 64 + swzi(row, ks2 * 32 + kg)];
      }
#pragma unroll
      for (int nt = 0; nt < 8; ++nt) {
        const int cc = wv * 128 + nt * 16 + l15;
        bw[nt] = *(const bf16x8*)(wproj_bf + (size_t)cc * 512 + h * 64 + ks2 * 32 + kg);
      }
#pragma unroll
      for (int mt = 0; mt < 4; ++mt)
#pragma unroll
        for (int nt = 0; nt < 8; ++nt)
          accF[mt][nt] = MFMA_BF16(ao[mt], bw[nt], accF[mt][nt]);
    }
  }
#pragma unroll
  for (int nt = 0; nt < 8; ++nt) {
    const int cc = wv * 128 + nt * 16 + l15;
    const float bp = bproj[cc];
#pragma unroll
    for (int mt = 0; mt < 4; ++mt) {
#pragma unroll
      for (int r = 0; r < 4; ++r) {
        const int row = MOFF[mt] + r4 + r;
        if (mt < 3 || (r4 + r) == 15) {
          out[((size_t)b * 50176 + (size_t)row * 1024 + (size_t)wi) * 512 + cc] =
              accF[mt][nt][r] + bp;
        }
      }
    }
  }
}

// ---------------------------------------------------------------------------
extern "C" void kernel_launch(void* const* d_in, const int* in_sizes, int n_in,
                              void* d_out, int out_size, void* d_ws, size_t ws_size,
                              hipStream_t stream) {
  const float* x      = (const float*)d_in[0];
  const float* w_qkv  = (const float*)d_in[1];
  const float* b_qkv  = (const float*)d_in[2];
  const float* w_proj = (const float*)d_in[3];
  const float* b_proj = (const float*)d_in[4];
  float* outp = (float*)d_out;

  const size_t QKV_E = (size_t)200704 * 1536;
  const size_t O_E   = (size_t)200704 * 512;
  const size_t NEED  = (QKV_E + O_E + 786432 + 262144) * 2 + 1536 * 4;

  if (ws_size >= NEED) {
    __bf16* qkv      = (__bf16*)d_ws;
    __bf16* xbuf     = qkv + QKV_E;      // x_bf16 (window-major)
    __bf16* wqkv_bf  = xbuf + O_E;
    __bf16* wproj_bf = wqkv_bf + 786432;
    float*  bq_s     = (float*)(wproj_bf + 262144);

    prep_weights<<<512, 256, 0, stream>>>(w_qkv, b_qkv, w_proj, wqkv_bf, wproj_bf, bq_s);
    prep_x<<<2048, 256, 0, stream>>>(x, xbuf);       // x -> bf16, window-major
    // QKV: M=200704 (784 tiles), N=1536 (6 tiles)
    gemm256<false, false><<<784 * 6, 512, 0, stream>>>(xbuf, wqkv_bf, bq_s, qkv, 784, 6);
    // fused attention + proj (writes token-major fp32 out directly)
    attn_proj<<<4096, 512, 0, stream>>>(qkv, wproj_bf, b_proj, outp);
  } else {
    __bf16* wqkv_bf  = (__bf16*)d_ws;
    __bf16* wproj_bf = wqkv_bf + 1536 * 512;
    float*  bq_s     = (float*)(wproj_bf + 512 * 512);
    prep_weights<<<1024, 256, 0, stream>>>(w_qkv, b_qkv, w_proj, wqkv_bf, wproj_bf, bq_s);
    swin_attn_fused<<<4096, 256, 0, stream>>>(x, wqkv_bf, bq_s, wproj_bf, b_proj, outp);
  }
}

// Round 12
// 981.322 us; speedup vs baseline: 1.2059x; 1.2059x over previous
//
#include <hip/hip_runtime.h>
#include <cstdint>
#include <cstddef>

// ---------------------------------------------------------------------------
// ShuffleWindowAttention, MI355X (gfx950)
// B=4, N=50176, C=512, WS=49, w=1024 windows/batch, NH=8, hd=64
// Pipeline (window-major intermediates):
//   prep_weights ; prep_x (fp32->bf16, token->window-major gather)
//   -> QKV GEMM (256^2, R9 counted-vmcnt schedule) -> windowed attention
//   -> proj GEMM (same template, row-permuted fp32 store to token-major out).
// R12 = R9 pipeline verbatim + vT double-XOR swizzle in attn_win
//       (fixes the 64-way bank conflict on V-transpose staging writes:
//        bank depended only on (s, j); adding n>>3 spreads across lanes).
// ---------------------------------------------------------------------------

typedef __bf16 bf16x8 __attribute__((ext_vector_type(8)));
typedef __bf16 bf16x4 __attribute__((ext_vector_type(4)));
typedef float  f32x4  __attribute__((ext_vector_type(4)));

#define MFMA_BF16(a, b, c) __builtin_amdgcn_mfma_f32_16x16x32_bf16((a), (b), (c), 0, 0, 0)

static __device__ __forceinline__ int swzi(int row, int col) {
  return col ^ ((row & 7) << 3);   // sP swizzle (128B rows)
}
// vT swizzle: chunk ^= (n&7) ^ (n>>3)  -> write banks spread across lanes,
// bv reads stay 16B-contiguous and 2-way (free).
static __device__ __forceinline__ int vswz(int n, int k) {
  return k ^ (((n ^ (n >> 3)) & 7) << 3);
}

typedef __attribute__((address_space(1))) const void gconst_t;
typedef __attribute__((address_space(3))) void lds_t;
static __device__ __forceinline__ void gload16(const void* g, void* l) {
  __builtin_amdgcn_global_load_lds((gconst_t*)g, (lds_t*)l, 16, 0, 0);
}

#define WAITV2()   asm volatile("s_waitcnt vmcnt(2)" ::: "memory")
#define WAITV0()   asm volatile("s_waitcnt vmcnt(0)" ::: "memory")

// window-major row -> token row
static __device__ __forceinline__ int wm2tok(int m) {
  const int b   = m / 50176;
  const int rem = m - b * 50176;
  const int wi  = rem / 49;
  const int s   = rem - wi * 49;
  return b * 50176 + s * 1024 + wi;
}

// ---------------------------------------------------------------------------
__global__ void prep_weights(const float* __restrict__ wqkv,
                             const float* __restrict__ bqkv,
                             const float* __restrict__ wproj,
                             __bf16* __restrict__ wqkv_bf,
                             __bf16* __restrict__ wproj_bf,
                             float* __restrict__ bq_s) {
  const int stride = gridDim.x * blockDim.x;
  const int t0 = blockIdx.x * blockDim.x + threadIdx.x;
  for (int i = t0; i < 1536 * 512; i += stride) {
    float v = wqkv[i];
    if (i < 512 * 512) v *= 0.125f;
    wqkv_bf[i] = (__bf16)v;
  }
  for (int i = t0; i < 512 * 512; i += stride) wproj_bf[i] = (__bf16)wproj[i];
  for (int i = t0; i < 1536; i += stride)      bq_s[i] = (i < 512 ? 0.125f : 1.0f) * bqkv[i];
}

// x: fp32 token-major [200704][512] -> bf16 WINDOW-MAJOR [200704][512]
__global__ void prep_x(const float* __restrict__ x, __bf16* __restrict__ xb) {
  const size_t total  = (size_t)200704 * 64;   // 8-elem groups
  const size_t stride = (size_t)gridDim.x * blockDim.x;
  for (size_t i = (size_t)blockIdx.x * blockDim.x + threadIdx.x; i < total; i += stride) {
    const int m  = (int)(i >> 6);              // window-major out row
    const int c8 = ((int)i & 63) * 8;
    const size_t t = (size_t)wm2tok(m);        // token-major src row
    const float4 a = *(const float4*)(x + t * 512 + c8);
    const float4 b = *(const float4*)(x + t * 512 + c8 + 4);
    bf16x8 v;
    v[0] = (__bf16)a.x; v[1] = (__bf16)a.y; v[2] = (__bf16)a.z; v[3] = (__bf16)a.w;
    v[4] = (__bf16)b.x; v[5] = (__bf16)b.y; v[6] = (__bf16)b.z; v[7] = (__bf16)b.w;
    *(bf16x8*)(xb + i * 8) = v;
  }
}

// ---------------------------------------------------------------------------
// 256x256-tile GEMM (R9 schedule, verbatim): counted WAITV(2) tile gate,
// staggered half-tile staging through drift phases, end-of-tile barrier.
// ---------------------------------------------------------------------------
template<bool OUT_F32, bool PERM_OUT>
__launch_bounds__(512, 2)
__global__ void gemm256(const __bf16* __restrict__ Ab,   // [M][512]
                        const __bf16* __restrict__ Bw,   // [N][512]
                        const float* __restrict__ bias,  // [N]
                        void* __restrict__ Cv,
                        int Mtiles, int Ntiles) {
  __shared__ __align__(16) __bf16 sA[2][256 * 64];
  __shared__ __align__(16) __bf16 sB[2][256 * 64];

  const int tid  = threadIdx.x;
  const int lane = tid & 63;
  const int l15  = lane & 15;
  const int kgc  = (lane >> 4) & 3;     // k-chunk within 32-k slice
  const int r4   = kgc * 4;             // C/D row group
  const int wv   = tid >> 6;            // 0..7
  const int wm   = wv >> 2, wn = wv & 3;

  const int nwg = Mtiles * Ntiles;
  const int cpx = nwg >> 3;                       // nwg % 8 == 0
  const int wg  = (blockIdx.x & 7) * cpx + (blockIdx.x >> 3);
  const int mt  = wg / Ntiles;                    // M-outer: A-tile L2 reuse
  const int nt  = wg % Ntiles;
  const size_t m0 = (size_t)mt * 256;
  const int    n0 = nt * 256;

  const int srow   = tid >> 3;                    // 0..63
  const int schunk = (tid & 7) ^ (srow & 7);

  f32x4 acc[8][4];
  const f32x4 zf = {0.f, 0.f, 0.f, 0.f};
#pragma unroll
  for (int i = 0; i < 8; ++i)
#pragma unroll
    for (int j = 0; j < 4; ++j) acc[i][j] = zf;

  auto STAGE_HALF = [&](int bufi, int kt, int mat, int h) {
    const size_t kof = (size_t)kt * 64 + schunk * 8;
    const __bf16* src = mat ? Bw : Ab;
    const size_t base0 = mat ? (size_t)n0 : m0;
    __bf16* dst = (mat ? &sB[bufi][0] : &sA[bufi][0]) + h * 8192 + tid * 8;
#pragma unroll
    for (int j = 0; j < 2; ++j)
      gload16(src + (base0 + (size_t)(h * 128 + j * 64 + srow)) * 512 + kof,
              dst + j * 4096);
  };

  auto LDB = [&](int bufi, int ks, bf16x8* bfrag) {
#pragma unroll
    for (int n = 0; n < 4; ++n) {
      const int r = wn * 64 + n * 16 + l15;
      bfrag[n] = *(const bf16x8*)&sB[bufi][r * 64 + (((ks * 4 + kgc) ^ (r & 7)) * 8)];
    }
  };
  auto LDA = [&](int bufi, int mh, int ks, bf16x8* afrag) {
#pragma unroll
    for (int m2 = 0; m2 < 4; ++m2) {
      const int r = wm * 128 + mh * 64 + m2 * 16 + l15;
      afrag[m2] = *(const bf16x8*)&sA[bufi][r * 64 + (((ks * 4 + kgc) ^ (r & 7)) * 8)];
    }
  };
  auto MM = [&](int mh, const bf16x8* afrag, const bf16x8* bfrag) {
    __builtin_amdgcn_s_setprio(1);
#pragma unroll
    for (int m2 = 0; m2 < 4; ++m2)
#pragma unroll
      for (int n = 0; n < 4; ++n)
        acc[mh * 4 + m2][n] = MFMA_BF16(afrag[m2], bfrag[n], acc[mh * 4 + m2][n]);
    __builtin_amdgcn_s_setprio(0);
  };

  // prologue: all 4 half-tiles of K-tile 0 -> buf 0 (8 loads in flight)
  STAGE_HALF(0, 0, 0, 0); STAGE_HALF(0, 0, 0, 1);
  STAGE_HALF(0, 0, 1, 0); STAGE_HALF(0, 0, 1, 1);

  int buf = 0;
  for (int t = 0; t < 8; ++t) {
    const int nxt = buf ^ 1;
    if (t < 7) { STAGE_HALF(nxt, t + 1, 0, 0); WAITV2(); }
    else       { WAITV0(); }
    __builtin_amdgcn_s_barrier();
    __builtin_amdgcn_sched_barrier(0);

    bf16x8 b0[4], b1[4], a[4];
    // phase 0: (ks0, mh0)
    LDB(buf, 0, b0);
    LDA(buf, 0, 0, a);
    MM(0, a, b0);
    // phase 1: (ks0, mh1)   + stage Ah1(t+1)
    if (t < 7) STAGE_HALF(nxt, t + 1, 0, 1);
    LDA(buf, 1, 0, a);
    MM(1, a, b0);
    // phase 2: (ks1, mh0)   + stage Bh0(t+1)
    if (t < 7) STAGE_HALF(nxt, t + 1, 1, 0);
    LDB(buf, 1, b1);
    LDA(buf, 0, 1, a);
    MM(0, a, b1);
    // phase 3: (ks1, mh1)   + stage Bh1(t+1)
    if (t < 7) STAGE_HALF(nxt, t + 1, 1, 1);
    LDA(buf, 1, 1, a);
    MM(1, a, b1);

    // end-of-tile barrier: all waves done reading buf
    __builtin_amdgcn_sched_barrier(0);
    __builtin_amdgcn_s_barrier();
    buf = nxt;
  }

  // ---- epilogue ----
  const int Nld = Ntiles * 256;
#pragma unroll
  for (int m = 0; m < 8; ++m) {
#pragma unroll
    for (int r = 0; r < 4; ++r) {
      const int row = (int)m0 + wm * 128 + m * 16 + r4 + r;   // window-major
      const size_t orow = PERM_OUT ? (size_t)wm2tok(row) : (size_t)row;
#pragma unroll
      for (int n = 0; n < 4; ++n) {
        const int col = n0 + wn * 64 + n * 16 + l15;
        const float v = acc[m][n][r] + bias[col];
        if (OUT_F32) ((float*)Cv)[orow * (size_t)Nld + col] = v;
        else         ((__bf16*)Cv)[orow * (size_t)Nld + col] = (__bf16)v;
      }
    }
  }
}

// ---------------------------------------------------------------------------
// Windowed attention: one block (8 waves) per window, wave = head.
// qkv WINDOW-MAJOR [blk*49 + s][1536] bf16 in;  O WINDOW-MAJOR [.][512] out.
// vT uses vswz (double-XOR) -> V-stage writes 8-way instead of 64-way.
// ---------------------------------------------------------------------------
__launch_bounds__(512)
__global__ void attn_win(const __bf16* __restrict__ qkv, __bf16* __restrict__ O) {
  __shared__ __align__(16) __bf16 vT[8 * 64 * 64];   // [h][n][vswz(n,k)]
  __shared__ __align__(16) __bf16 sP[8][16 * 64];    // per-wave P tile

  const int tid  = threadIdx.x;
  const int lane = tid & 63;
  const int h    = tid >> 6;                 // wave = head
  const int l15  = lane & 15;
  const int kg   = ((lane >> 4) & 3) * 8;
  const int r4   = ((lane >> 4) & 3) * 4;

  const size_t wbase = (size_t)blockIdx.x * 49;   // window-major row base

  const int MOFF[4] = {0, 16, 32, 33};
  const float NEG_INF = -__builtin_inff();

  // ---- issue q,k fragment loads early (overlap with V staging) ----
  bf16x8 aq[4][2], bk[4][2];
#pragma unroll
  for (int mt = 0; mt < 4; ++mt) {
    const size_t tok = wbase + (size_t)(MOFF[mt] + l15);
#pragma unroll
    for (int ks = 0; ks < 2; ++ks) {
      aq[mt][ks] = *(const bf16x8*)(qkv + tok * 1536 +       h * 64 + ks * 32 + kg);
      bk[mt][ks] = *(const bf16x8*)(qkv + tok * 1536 + 512 + h * 64 + ks * 32 + kg);
    }
  }

  // ---- zero vT pad rows k = 49..63 ----
  for (int i = tid; i < 8 * 64 * 16; i += 512) {
    const int k = 48 + (i & 15);
    if (k != 48) {
      const int n  = (i >> 4) & 63;
      const int hh = i >> 10;
      vT[hh * 4096 + n * 64 + vswz(n, k)] = (__bf16)0.0f;
    }
  }
  // ---- stage V transposed (+swizzled); reads fully contiguous ----
  for (int i = tid; i < 49 * 64; i += 512) {
    const int s  = i >> 6;
    const int c8 = (i & 63) * 8;
    bf16x8 v8 = *(const bf16x8*)(qkv + (wbase + s) * 1536 + 1024 + c8);
    const int hh = c8 >> 6;
#pragma unroll
    for (int j = 0; j < 8; ++j) {
      const int n = (c8 & 63) + j;
      vT[hh * 4096 + n * 64 + vswz(n, s)] = v8[j];
    }
  }
  __syncthreads();

  // ---- V fragments (2-way/free via vswz) ----
  bf16x8 bv[4][2];
#pragma unroll
  for (int ntv = 0; ntv < 4; ++ntv) {
    const int n = ntv * 16 + l15;
#pragma unroll
    for (int ks = 0; ks < 2; ++ks)
      bv[ntv][ks] = *(const bf16x8*)&vT[h * 4096 + n * 64 + vswz(n, ks * 32 + kg)];
  }

  // ---- S = q k^T ----
  f32x4 accS[4][4];
  const f32x4 zf = {0.f, 0.f, 0.f, 0.f};
#pragma unroll
  for (int m = 0; m < 4; ++m)
#pragma unroll
    for (int n = 0; n < 4; ++n) accS[m][n] = zf;
#pragma unroll
  for (int ks = 0; ks < 2; ++ks)
#pragma unroll
    for (int m = 0; m < 4; ++m)
#pragma unroll
      for (int n = 0; n < 4; ++n)
        accS[m][n] = MFMA_BF16(aq[m][ks], bk[n][ks], accS[m][n]);

  // ---- per row-tile: softmax -> P (LDS) -> PV -> store O ----
#pragma unroll
  for (int mt = 0; mt < 4; ++mt) {
#pragma unroll
    for (int r = 0; r < 4; ++r) {
      const int prow = r4 + r;
      const float sv0 = accS[mt][0][r];
      const float sv1 = accS[mt][1][r];
      const float sv2 = accS[mt][2][r];
      const float sv3 = (l15 == 15) ? accS[mt][3][r] : NEG_INF;
      float mx = fmaxf(fmaxf(sv0, sv1), fmaxf(sv2, sv3));
      mx = fmaxf(mx, __shfl_xor(mx, 1));
      mx = fmaxf(mx, __shfl_xor(mx, 2));
      mx = fmaxf(mx, __shfl_xor(mx, 4));
      mx = fmaxf(mx, __shfl_xor(mx, 8));
      const float e0 = __expf(sv0 - mx);
      const float e1 = __expf(sv1 - mx);
      const float e2 = __expf(sv2 - mx);
      const float e3 = __expf(sv3 - mx);      // 0 for masked lanes
      float sum = e0 + e1 + e2 + e3;
      sum += __shfl_xor(sum, 1);
      sum += __shfl_xor(sum, 2);
      sum += __shfl_xor(sum, 4);
      sum += __shfl_xor(sum, 8);
      const float inv = 1.0f / sum;
      sP[h][prow * 64 + swzi(prow, 0  + l15)] = (__bf16)(e0 * inv);
      sP[h][prow * 64 + swzi(prow, 16 + l15)] = (__bf16)(e1 * inv);
      sP[h][prow * 64 + swzi(prow, 32 + l15)] = (__bf16)(e2 * inv);
      if (l15 == 15) sP[h][prow * 64 + swzi(prow, 48)] = (__bf16)(e3 * inv);
      if (l15 < 15)  sP[h][prow * 64 + swzi(prow, 49 + l15)] = (__bf16)0.0f;
    }
    bf16x8 ap[2];
#pragma unroll
    for (int ks = 0; ks < 2; ++ks)
      ap[ks] = *(const bf16x8*)&sP[h][l15 * 64 + swzi(l15, ks * 32 + kg)];
    f32x4 accO[4];
#pragma unroll
    for (int n = 0; n < 4; ++n) accO[n] = zf;
#pragma unroll
    for (int ks = 0; ks < 2; ++ks)
#pragma unroll
      for (int n = 0; n < 4; ++n)
        accO[n] = MFMA_BF16(ap[ks], bv[n][ks], accO[n]);
#pragma unroll
    for (int n = 0; n < 4; ++n) {
#pragma unroll
      for (int r = 0; r < 4; ++r) {
        const int row = MOFF[mt] + r4 + r;
        O[(wbase + row) * 512 + h * 64 + n * 16 + l15] = (__bf16)accO[n][r];
      }
    }
  }
}

// ===========================================================================
// Fallback: round-1 fused kernel (used only if ws_size is too small).
// ===========================================================================
__launch_bounds__(256, 2)
__global__ void swin_attn_fused(const float* __restrict__ x,
                                const __bf16* __restrict__ wqkv_bf,
                                const float* __restrict__ bq_s,
                                const __bf16* __restrict__ wproj_bf,
                                const float* __restrict__ bproj,
                                float* __restrict__ out) {
  __shared__ __align__(16) __bf16 s_xw[49 * 512];
  __shared__ __align__(16) __bf16 s_q [49 * 64];
  __shared__ __align__(16) __bf16 s_k [49 * 64];
  __shared__ __align__(16) __bf16 s_vT[64 * 64];
  __shared__ __align__(16) __bf16 s_p [49 * 64];

  const int tid  = threadIdx.x;
  const int lane = tid & 63;
  const int wv   = tid >> 6;
  const int l15  = lane & 15;
  const int kg   = (lane >> 4) * 8;
  const int r4   = (lane >> 4) * 4;
  const int blk = blockIdx.x;
  const int b   = blk >> 10;
  const int wi  = blk & 1023;
  const int MOFF[4] = {0, 16, 32, 33};
  const float NEG_INF = -__builtin_inff();

  for (int i = tid; i < 64 * 64; i += 256) s_vT[i] = (__bf16)0.0f;
  const float* xwin = x + ((size_t)b * 50176 + (size_t)wi) * 512;
  for (int idx = tid; idx < 49 * 128; idx += 256) {
    const int row = idx >> 7;
    const int c4  = (idx & 127) * 4;
    const float4 v = *(const float4*)(xwin + (size_t)row * (1024 * 512) + c4);
    bf16x4 t;
    t.x = (__bf16)v.x; t.y = (__bf16)v.y; t.z = (__bf16)v.z; t.w = (__bf16)v.w;
    *(bf16x4*)&s_xw[row * 512 + swzi(row, c4)] = t;
  }
  f32x4 accF[4][8];
  const f32x4 zf = {0.f, 0.f, 0.f, 0.f};
#pragma unroll
  for (int m = 0; m < 4; ++m)
#pragma unroll
    for (int n = 0; n < 8; ++n) accF[m][n] = zf;
  __syncthreads();

  for (int h = 0; h < 8; ++h) {
    f32x4 accA[4][3];
#pragma unroll
    for (int m = 0; m < 4; ++m)
#pragma unroll
      for (int n = 0; n < 3; ++n) accA[m][n] = zf;
    const __bf16* pB[3];
    float biasv[3];
#pragma unroll
    for (int nt = 0; nt < 3; ++nt) {
      const int c  = wv * 48 + nt * 16 + l15;
      const int wr = (c < 64) ? (h * 64 + c)
                   : (c < 128) ? (512 + h * 64 + (c - 64))
                               : (1024 + h * 64 + (c - 128));
      pB[nt]    = wqkv_bf + (size_t)wr * 512 + kg;
      biasv[nt] = bq_s[wr];
    }
#pragma unroll
    for (int ks = 0; ks < 16; ++ks) {
      bf16x8 a[4], bb[3];
#pragma unroll
      for (int mt = 0; mt < 4; ++mt) {
        const int row = MOFF[mt] + l15;
        a[mt] = *(const bf16x8*)&s_xw[row * 512 + swzi(row, ks * 32 + kg)];
      }
#pragma unroll
      for (int nt = 0; nt < 3; ++nt) bb[nt] = *(const bf16x8*)(pB[nt] + ks * 32);
#pragma unroll
      for (int mt = 0; mt < 4; ++mt)
#pragma unroll
        for (int nt = 0; nt < 3; ++nt)
          accA[mt][nt] = MFMA_BF16(a[mt], bb[nt], accA[mt][nt]);
    }
#pragma unroll
    for (int nt = 0; nt < 3; ++nt) {
      const int c = wv * 48 + nt * 16 + l15;
#pragma unroll
      for (int mt = 0; mt < 4; ++mt) {
#pragma unroll
        for (int r = 0; r < 4; ++r) {
          const int row = MOFF[mt] + r4 + r;
          const __bf16 bvv = (__bf16)(accA[mt][nt][r] + biasv[nt]);
          if (c < 64)       s_q[row * 64 + swzi(row, c)] = bvv;
          else if (c < 128) s_k[row * 64 + swzi(row, c - 64)] = bvv;
          else {
            const int vr = c - 128;
            s_vT[vr * 64 + swzi(vr, row)] = bvv;
          }
        }
      }
    }
    __syncthreads();

    const int R = MOFF[wv];
    bf16x8 aq[2], bkf[4][2];
#pragma unroll
    for (int ks2 = 0; ks2 < 2; ++ks2) {
      const int row = R + l15;
      aq[ks2] = *(const bf16x8*)&s_q[row * 64 + swzi(row, ks2 * 32 + kg)];
    }
#pragma unroll
    for (int nt = 0; nt < 4; ++nt) {
      const int row = MOFF[nt] + l15;
#pragma unroll
      for (int ks2 = 0; ks2 < 2; ++ks2)
        bkf[nt][ks2] = *(const bf16x8*)&s_k[row * 64 + swzi(row, ks2 * 32 + kg)];
    }
    f32x4 accS[4];
#pragma unroll
    for (int n = 0; n < 4; ++n) accS[n] = zf;
#pragma unroll
    for (int ks2 = 0; ks2 < 2; ++ks2)
#pragma unroll
      for (int nt = 0; nt < 4; ++nt)
        accS[nt] = MFMA_BF16(aq[ks2], bkf[nt][ks2], accS[nt]);
#pragma unroll
    for (int r = 0; r < 4; ++r) {
      const int row = R + r4 + r;
      const float sv0 = accS[0][r];
      const float sv1 = accS[1][r];
      const float sv2 = accS[2][r];
      const float sv3 = (l15 == 15) ? accS[3][r] : NEG_INF;
      float m = fmaxf(fmaxf(sv0, sv1), fmaxf(sv2, sv3));
      m = fmaxf(m, __shfl_xor(m, 1));
      m = fmaxf(m, __shfl_xor(m, 2));
      m = fmaxf(m, __shfl_xor(m, 4));
      m = fmaxf(m, __shfl_xor(m, 8));
      const float e0 = __expf(sv0 - m);
      const float e1 = __expf(sv1 - m);
      const float e2 = __expf(sv2 - m);
      const float e3 = __expf(sv3 - m);
      float s = e0 + e1 + e2 + e3;
      s += __shfl_xor(s, 1);
      s += __shfl_xor(s, 2);
      s += __shfl_xor(s, 4);
      s += __shfl_xor(s, 8);
      const float inv = 1.0f / s;
      s_p[row * 64 + swzi(row, 0  + l15)] = (__bf16)(e0 * inv);
      s_p[row * 64 + swzi(row, 16 + l15)] = (__bf16)(e1 * inv);
      s_p[row * 64 + swzi(row, 32 + l15)] = (__bf16)(e2 * inv);
      if (l15 == 15) s_p[row * 64 + swzi(row, 48)] = (__bf16)(e3 * inv);
      if (l15 < 15)  s_p[row * 64 + swzi(row, 49 + l15)] = (__bf16)0.0f;
    }
    bf16x8 ap[2], bv2[4][2];
#pragma unroll
    for (int ks2 = 0; ks2 < 2; ++ks2) {
      const int row = R + l15;
      ap[ks2] = *(const bf16x8*)&s_p[row * 64 + swzi(row, ks2 * 32 + kg)];
    }
#pragma unroll
    for (int nt = 0; nt < 4; ++nt) {
      const int row = nt * 16 + l15;
#pragma unroll
      for (int ks2 = 0; ks2 < 2; ++ks2)
        bv2[nt][ks2] = *(const bf16x8*)&s_vT[row * 64 + swzi(row, ks2 * 32 + kg)];
    }
    __syncthreads();
    f32x4 accO[4];
#pragma unroll
    for (int n = 0; n < 4; ++n) accO[n] = zf;
#pragma unroll
    for (int ks2 = 0; ks2 < 2; ++ks2)
#pragma unroll
      for (int nt = 0; nt < 4; ++nt)
        accO[nt] = MFMA_BF16(ap[ks2], bv2[nt][ks2], accO[nt]);
#pragma unroll
    for (int nt = 0; nt < 4; ++nt) {
#pragma unroll
      for (int r = 0; r < 4; ++r) {
        const int row = R + r4 + r;
        s_p[row * 64 + swzi(row, nt * 16 + l15)] = (__bf16)accO[nt][r];
      }
    }
    __syncthreads();
#pragma unroll
    for (int ks2 = 0; ks2 < 2; ++ks2) {
      bf16x8 ao[4], bw[8];
#pragma unroll
      for (int mt = 0; mt < 4; ++mt) {
        const int row = MOFF[mt] + l15;
        ao[mt] = *(const bf16x8*)&s_p[row * 64 + swzi(row, ks2 * 32 + kg)];
      }
#pragma unroll
      for (int nt = 0; nt < 8; ++nt) {
        const int cc = wv * 128 + nt * 16 + l15;
        bw[nt] = *(const bf16x8*)(wproj_bf + (size_t)cc * 512 + h * 64 + ks2 * 32 + kg);
      }
#pragma unroll
      for (int mt = 0; mt < 4; ++mt)
#pragma unroll
        for (int nt = 0; nt < 8; ++nt)
          accF[mt][nt] = MFMA_BF16(ao[mt], bw[nt], accF[mt][nt]);
    }
  }
#pragma unroll
  for (int nt = 0; nt < 8; ++nt) {
    const int cc = wv * 128 + nt * 16 + l15;
    const float bp = bproj[cc];
#pragma unroll
    for (int mt = 0; mt < 4; ++mt) {
#pragma unroll
      for (int r = 0; r < 4; ++r) {
        const int row = MOFF[mt] + r4 + r;
        if (mt < 3 || (r4 + r) == 15) {
          out[((size_t)b * 50176 + (size_t)row * 1024 + (size_t)wi) * 512 + cc] =
              accF[mt][nt][r] + bp;
        }
      }
    }
  }
}

// ---------------------------------------------------------------------------
extern "C" void kernel_launch(void* const* d_in, const int* in_sizes, int n_in,
                              void* d_out, int out_size, void* d_ws, size_t ws_size,
                              hipStream_t stream) {
  const float* x      = (const float*)d_in[0];
  const float* w_qkv  = (const float*)d_in[1];
  const float* b_qkv  = (const float*)d_in[2];
  const float* w_proj = (const float*)d_in[3];
  const float* b_proj = (const float*)d_in[4];
  float* outp = (float*)d_out;

  const size_t QKV_E = (size_t)200704 * 1536;
  const size_t O_E   = (size_t)200704 * 512;
  const size_t NEED  = (QKV_E + O_E + 786432 + 262144) * 2 + 1536 * 4;

  if (ws_size >= NEED) {
    __bf16* qkv      = (__bf16*)d_ws;
    __bf16* Obuf     = qkv + QKV_E;      // holds x_bf16 first, then attn output
    __bf16* wqkv_bf  = Obuf + O_E;
    __bf16* wproj_bf = wqkv_bf + 786432;
    float*  bq_s     = (float*)(wproj_bf + 262144);

    prep_weights<<<512, 256, 0, stream>>>(w_qkv, b_qkv, w_proj, wqkv_bf, wproj_bf, bq_s);
    prep_x<<<2048, 256, 0, stream>>>(x, Obuf);       // x -> bf16, window-major
    // QKV: M=200704 (784 tiles), N=1536 (6 tiles)
    gemm256<false, false><<<784 * 6, 512, 0, stream>>>(Obuf, wqkv_bf, bq_s, qkv, 784, 6);
    attn_win<<<4096, 512, 0, stream>>>(qkv, Obuf);   // overwrites x_bf16
    // proj: M=200704 (784 tiles), N=512 (2 tiles); permuted store to token-major
    gemm256<true, true><<<784 * 2, 512, 0, stream>>>(Obuf, wproj_bf, b_proj, outp, 784, 2);
  } else {
    __bf16* wqkv_bf  = (__bf16*)d_ws;
    __bf16* wproj_bf = wqkv_bf + 1536 * 512;
    float*  bq_s     = (float*)(wproj_bf + 512 * 512);
    prep_weights<<<1024, 256, 0, stream>>>(w_qkv, b_qkv, w_proj, wqkv_bf, wproj_bf, bq_s);
    swin_attn_fused<<<4096, 256, 0, stream>>>(x, wqkv_bf, bq_s, wproj_bf, b_proj, outp);
  }
}